// Round 1
// baseline (437.409 us; speedup 1.0000x reference)
//
#include <hip/hip_runtime.h>
#include <stdint.h>

#pragma clang fp contract(off)

#define BB 16
#define NN 25200
#define ROW 85
#define NCLS 80
#define TK 2048
#define MAXDET 1000
#define CONF 0.25f
#define IOUT 0.45f
#define MAXWH 4096.0f

// ---------------- Stage 1: scores + argmax class ----------------
__global__ __launch_bounds__(256) void score_kernel(const float* __restrict__ pred,
                                                    float* __restrict__ scores,
                                                    int* __restrict__ cls) {
  int n = blockIdx.x * blockDim.x + threadIdx.x;
  int b = blockIdx.y;
  if (n >= NN) return;
  const float* row = pred + ((size_t)b * NN + n) * ROW;
  float obj = row[4];
  float best = row[5];
  int bid = 0;
  for (int c = 1; c < NCLS; ++c) {
    float p = row[5 + c];
    if (p > best) { best = p; bid = c; }
  }
  float score = obj * best;
  bool valid = (obj > CONF) && (score > CONF);
  scores[(size_t)b * NN + n] = valid ? score : 0.0f;
  cls[(size_t)b * NN + n] = bid;
}

// ---------------- Stage 2: stable top-2048 (radix select + bitonic sort) ----------------
__global__ __launch_bounds__(1024) void select_kernel(const float* __restrict__ pred,
                                                      const float* __restrict__ scores,
                                                      const int* __restrict__ cls,
                                                      float* __restrict__ tops,
                                                      float* __restrict__ boxes,
                                                      int* __restrict__ clsk) {
  int b = blockIdx.x;
  int t = threadIdx.x;
  const float* sc = scores + (size_t)b * NN;

  __shared__ unsigned int hist[256];
  __shared__ unsigned int bc[2];
  __shared__ int scnt[1024];
  __shared__ unsigned long long skey[TK];
  __shared__ int gtc;

  // --- radix select: find bits of the 2048th-largest score ---
  unsigned int prefix = 0, pmask = 0;
  int r = TK;  // 1-based rank from the top
  for (int shift = 24; shift >= 0; shift -= 8) {
    if (t < 256) hist[t] = 0;
    __syncthreads();
    for (int n = t; n < NN; n += 1024) {
      unsigned int u = __float_as_uint(sc[n]);
      if ((u & pmask) == prefix) atomicAdd(&hist[(u >> shift) & 255u], 1u);
    }
    __syncthreads();
    if (t == 0) {
      int cum = 0;
      for (int d = 255; d >= 0; --d) {
        int c = (int)hist[d];
        if (cum + c >= r) { bc[0] = (unsigned)d; bc[1] = (unsigned)(r - cum); break; }
        cum += c;
      }
    }
    __syncthreads();
    prefix |= bc[0] << shift;
    pmask |= 255u << shift;
    r = (int)bc[1];
    __syncthreads();
  }
  unsigned int pivot = prefix;
  int keq = r;          // how many pivot-equal items to take (stable, lowest index)
  int cgt = TK - keq;   // count of strictly-greater items

  // --- gather: >pivot unordered, ==pivot stably by index ---
  if (t == 0) gtc = 0;
  const int CH = 25;  // 1024*25 = 25600 >= 25200
  int begin = t * CH;
  int end = begin + CH; if (end > NN) end = NN;
  int cnt = 0;
  for (int n = begin; n < end; ++n) {
    if (__float_as_uint(sc[n]) == pivot) ++cnt;
  }
  scnt[t] = cnt;
  __syncthreads();
  for (int off = 1; off < 1024; off <<= 1) {
    int v = (t >= off) ? scnt[t - off] : 0;
    __syncthreads();
    scnt[t] += v;
    __syncthreads();
  }
  int eqoff = scnt[t] - cnt;  // exclusive prefix: stable global rank among eq items
  for (int n = begin; n < end; ++n) {
    unsigned int u = __float_as_uint(sc[n]);
    if (u > pivot) {
      int slot = atomicAdd(&gtc, 1);
      skey[slot] = ((unsigned long long)u << 32) | (unsigned int)(~n);
    } else if (u == pivot) {
      if (eqoff < keq)
        skey[cgt + eqoff] = ((unsigned long long)u << 32) | (unsigned int)(~n);
      ++eqoff;
    }
  }
  __syncthreads();

  // --- bitonic sort descending on (score_bits, ~idx): matches stable top_k ---
  for (int k = 2; k <= TK; k <<= 1) {
    for (int j = k >> 1; j > 0; j >>= 1) {
      for (int i = t; i < TK; i += 1024) {
        int ixj = i ^ j;
        if (ixj > i) {
          unsigned long long a = skey[i], bval = skey[ixj];
          bool up = ((i & k) == 0);
          if (up ? (a < bval) : (a > bval)) { skey[i] = bval; skey[ixj] = a; }
        }
      }
      __syncthreads();
    }
  }

  // --- epilogue: tops, class, xyxy boxes for the 2048 selected ---
  for (int i = t; i < TK; i += 1024) {
    unsigned long long key = skey[i];
    unsigned int ub = (unsigned int)(key >> 32);
    int idx = (int)(~(unsigned int)key);
    tops[(size_t)b * TK + i] = __uint_as_float(ub);
    clsk[(size_t)b * TK + i] = cls[(size_t)b * NN + idx];
    const float* rowp = pred + ((size_t)b * NN + idx) * ROW;
    float cx = rowp[0], cy = rowp[1], w = rowp[2], h = rowp[3];
    float hw = w * 0.5f, hh = h * 0.5f;
    float* ob = boxes + ((size_t)b * TK + i) * 4;
    ob[0] = cx - hw; ob[1] = cy - hh; ob[2] = cx + hw; ob[3] = cy + hh;
  }
}

// ---------------- Stage 3: greedy NMS, one wave per (batch, class) ----------------
__global__ __launch_bounds__(64) void nms_kernel(const float* __restrict__ tops,
                                                 const float* __restrict__ boxes,
                                                 const int* __restrict__ clsk,
                                                 int* __restrict__ keep) {
  int c = blockIdx.x;
  int b = blockIdx.y;
  int lane = threadIdx.x;
  __shared__ float sx1[TK], sy1[TK], sx2[TK], sy2[TK];
  __shared__ unsigned short spos[TK];
  __shared__ unsigned char skp[TK];

  float shift = (float)c * MAXWH;
  int m = 0;
  for (int base = 0; base < TK; base += 64) {
    int j = base + lane;
    bool match = (clsk[(size_t)b * TK + j] == c);
    unsigned long long bal = __ballot(match);
    int mp = m + __popcll(bal & ((1ull << lane) - 1ull));
    if (match) {
      spos[mp] = (unsigned short)j;
      const float* bx = boxes + ((size_t)b * TK + j) * 4;
      // shifted boxes, exactly as reference: boxes_k + cls*4096 per coordinate
      sx1[mp] = bx[0] + shift;
      sy1[mp] = bx[1] + shift;
      sx2[mp] = bx[2] + shift;
      sy2[mp] = bx[3] + shift;
      skp[mp] = (tops[(size_t)b * TK + j] > 0.0f) ? 1 : 0;
    }
    m += (int)__popcll(bal);
  }
  __syncthreads();

  for (int i = 0; i < m; ++i) {
    __syncthreads();
    if (!skp[i]) continue;  // uniform across the wave
    float ax1 = sx1[i], ay1 = sy1[i], ax2 = sx2[i], ay2 = sy2[i];
    float aarea = (ax2 - ax1) * (ay2 - ay1);
    for (int j = i + 1 + lane; j < m; j += 64) {
      float bx1 = sx1[j], by1 = sy1[j], bx2 = sx2[j], by2 = sy2[j];
      float ltx = fmaxf(ax1, bx1), lty = fmaxf(ay1, by1);
      float rbx = fminf(ax2, bx2), rby = fminf(ay2, by2);
      float iw = fmaxf(rbx - ltx, 0.0f);
      float ih = fmaxf(rby - lty, 0.0f);
      float inter = iw * ih;
      float barea = (bx2 - bx1) * (by2 - by1);
      float iou = inter / (aarea + barea - inter + 1e-7f);
      if (iou > IOUT) skp[j] = 0;
    }
  }
  __syncthreads();

  for (int i = lane; i < m; i += 64) {
    keep[(size_t)b * TK + spos[i]] = skp[i];
  }
}

// ---------------- Stage 4: compact first 1000 kept + padding ----------------
__global__ __launch_bounds__(256) void out_kernel(const float* __restrict__ tops,
                                                  const float* __restrict__ boxes,
                                                  const int* __restrict__ clsk,
                                                  const int* __restrict__ keep,
                                                  float* __restrict__ out) {
  int b = blockIdx.x;
  int t = threadIdx.x;
  __shared__ int scnt[256];
  const int CH = TK / 256;  // 8
  int base = t * CH;
  int kp[CH];
  int cnt = 0;
  for (int k = 0; k < CH; ++k) {
    kp[k] = keep[(size_t)b * TK + base + k];
    cnt += kp[k];
  }
  scnt[t] = cnt;
  __syncthreads();
  for (int off = 1; off < 256; off <<= 1) {
    int v = (t >= off) ? scnt[t - off] : 0;
    __syncthreads();
    scnt[t] += v;
    __syncthreads();
  }
  int r = scnt[t] - cnt;
  int K = scnt[255];
  for (int k = 0; k < CH; ++k) {
    if (kp[k]) {
      if (r < MAXDET) {
        int j = base + k;
        float* o = out + ((size_t)b * MAXDET + r) * 6;
        const float* bx = boxes + ((size_t)b * TK + j) * 4;
        o[0] = bx[0]; o[1] = bx[1]; o[2] = bx[2]; o[3] = bx[3];
        o[4] = tops[(size_t)b * TK + j];
        o[5] = (float)clsk[(size_t)b * TK + j];
      }
      ++r;
    }
  }
  int Kc = K < MAXDET ? K : MAXDET;
  for (int r2 = Kc + t; r2 < MAXDET; r2 += 256) {
    float* o = out + ((size_t)b * MAXDET + r2) * 6;
    o[0] = 0.0f; o[1] = 0.0f; o[2] = 0.0f; o[3] = 0.0f; o[4] = 0.0f; o[5] = -1.0f;
  }
}

extern "C" void kernel_launch(void* const* d_in, const int* in_sizes, int n_in,
                              void* d_out, int out_size, void* d_ws, size_t ws_size,
                              hipStream_t stream) {
  const float* pred = (const float*)d_in[0];
  float* out = (float*)d_out;

  char* ws = (char*)d_ws;
  size_t off = 0;
  float* scores = (float*)(ws + off); off += (size_t)BB * NN * 4;        // 1.6 MB
  int*   cls    = (int*)(ws + off);   off += (size_t)BB * NN * 4;        // 1.6 MB
  float* tops   = (float*)(ws + off); off += (size_t)BB * TK * 4;        // 128 KB
  float* boxes  = (float*)(ws + off); off += (size_t)BB * TK * 16;       // 512 KB
  int*   clsk   = (int*)(ws + off);   off += (size_t)BB * TK * 4;        // 128 KB
  int*   keep   = (int*)(ws + off);   off += (size_t)BB * TK * 4;        // 128 KB
  (void)ws_size; (void)in_sizes; (void)n_in; (void)out_size;

  score_kernel<<<dim3((NN + 255) / 256, BB), 256, 0, stream>>>(pred, scores, cls);
  select_kernel<<<BB, 1024, 0, stream>>>(pred, scores, cls, tops, boxes, clsk);
  nms_kernel<<<dim3(NCLS, BB), 64, 0, stream>>>(tops, boxes, clsk, keep);
  out_kernel<<<BB, 256, 0, stream>>>(tops, boxes, clsk, keep, out);
}

// Round 2
// 331.072 us; speedup vs baseline: 1.3212x; 1.3212x over previous
//
#include <hip/hip_runtime.h>
#include <stdint.h>

#pragma clang fp contract(off)

#define BB 16
#define NN 25200
#define ROW 85
#define NCLS 80
#define TK 2048
#define SORTN 4096
#define NBIN 4096
#define MAXDET 1000
#define CONF 0.25f
#define IOUT 0.45f
#define MAXWH 4096.0f

typedef float fvec4 __attribute__((ext_vector_type(4)));
typedef fvec4 f4u __attribute__((aligned(4)));   // unaligned (4B) vector load

// ---------------- Stage 1: scores + argmax class + fused histogram ----------------
__global__ __launch_bounds__(256) void score_kernel(const float* __restrict__ pred,
                                                    float* __restrict__ scores,
                                                    int* __restrict__ cls,
                                                    unsigned int* __restrict__ hist) {
  int n = blockIdx.x * blockDim.x + threadIdx.x;
  int b = blockIdx.y;
  if (n >= NN) return;
  const float* row = pred + ((size_t)b * NN + n) * ROW;
  const f4u* vp = (const f4u*)(row + 4);  // floats 4..83 as 20 vec4
  float best;
  int bid;
  float obj;
  {
    fvec4 v0 = vp[0];           // obj, pr0, pr1, pr2
    obj = v0[0];
    best = v0[1]; bid = 0;
    if (v0[2] > best) { best = v0[2]; bid = 1; }
    if (v0[3] > best) { best = v0[3]; bid = 2; }
  }
#pragma unroll
  for (int i = 1; i < 20; ++i) {
    fvec4 v = vp[i];            // classes 4i-1 .. 4i+2
#pragma unroll
    for (int k = 0; k < 4; ++k) {
      float p = v[k];
      int c = 4 * i - 1 + k;
      if (p > best) { best = p; bid = c; }
    }
  }
  {
    float p = row[84];          // class 79
    if (p > best) { best = p; bid = 79; }
  }
  float score = obj * best;
  bool valid = (obj > CONF) && (score > CONF);
  float sout = valid ? score : 0.0f;
  scores[(size_t)b * NN + n] = sout;
  cls[(size_t)b * NN + n] = bid;
  if (valid) {
    unsigned int u = __float_as_uint(sout);   // in (0x3E800000, 0x3F800000]
    unsigned int bin = (u - 0x3E800001u) >> 12;
    if (bin > NBIN - 1) bin = NBIN - 1;       // safety (score > 1 impossible)
    atomicAdd(&hist[(size_t)b * NBIN + bin], 1u);
  }
}

// ---------------- Stage 2a: pivot bin per batch ----------------
__global__ __launch_bounds__(256) void pivot_kernel(const unsigned int* __restrict__ hist,
                                                    int* __restrict__ pivP) {
  int b = blockIdx.x;
  int t = threadIdx.x;
  const unsigned int* h = hist + (size_t)b * NBIN;
  __shared__ int csum[256];
  int s = 0;
  for (int k = 0; k < 16; ++k) s += (int)h[t * 16 + k];
  csum[t] = s;
  __syncthreads();
  if (t == 0) {
    int cum = 0;
    int P = 0;
    for (int c = 255; c >= 0; --c) {
      if (cum + csum[c] >= TK) {
        for (int bin = c * 16 + 15; bin >= c * 16; --bin) {
          cum += (int)h[bin];
          if (cum >= TK) { P = bin; break; }
        }
        break;
      }
      cum += csum[c];
    }
    pivP[b] = P;  // if total < TK (never with this data) P stays 0
  }
}

// ---------------- Stage 2b: gather candidates (bin >= P), sort, emit top-2048 ----------------
__global__ __launch_bounds__(1024) void gather_sort_kernel(const float* __restrict__ pred,
                                                           const float* __restrict__ scores,
                                                           const int* __restrict__ cls,
                                                           const int* __restrict__ pivP,
                                                           float* __restrict__ tops,
                                                           float* __restrict__ boxes,
                                                           int* __restrict__ clsk) {
  int b = blockIdx.x;
  int t = threadIdx.x;
  const float* sc = scores + (size_t)b * NN;
  __shared__ unsigned long long skey[SORTN];
  __shared__ int cnt;
  if (t == 0) cnt = 0;
  for (int i = t; i < SORTN; i += 1024) skey[i] = 0ull;
  __syncthreads();
  unsigned int P = (unsigned int)pivP[b];
  for (int n = t; n < NN; n += 1024) {
    unsigned int u = __float_as_uint(sc[n]);
    if (u > 0x3E800000u) {
      unsigned int bin = (u - 0x3E800001u) >> 12;
      if (bin > NBIN - 1) bin = NBIN - 1;
      if (bin >= P) {
        int slot = atomicAdd(&cnt, 1);
        if (slot < SORTN)
          skey[slot] = ((unsigned long long)u << 32) | (unsigned int)(~n);
      }
    }
  }
  __syncthreads();

  // bitonic sort SORTN keys descending on (score_bits, ~idx) — exact stable top_k order
  for (int k = 2; k <= SORTN; k <<= 1) {
    for (int j = k >> 1; j > 0; j >>= 1) {
      for (int i = t; i < SORTN; i += 1024) {
        int ixj = i ^ j;
        if (ixj > i) {
          unsigned long long a = skey[i], bv = skey[ixj];
          bool up = ((i & k) == 0);
          if (up ? (a < bv) : (a > bv)) { skey[i] = bv; skey[ixj] = a; }
        }
      }
      __syncthreads();
    }
  }

  for (int i = t; i < TK; i += 1024) {
    unsigned long long key = skey[i];
    unsigned int ub = (unsigned int)(key >> 32);
    float* ob = boxes + ((size_t)b * TK + i) * 4;
    if (ub == 0u) {  // padding (only if < 2048 valid — never with this data)
      tops[(size_t)b * TK + i] = 0.0f;
      clsk[(size_t)b * TK + i] = 0;
      ob[0] = 0.f; ob[1] = 0.f; ob[2] = 0.f; ob[3] = 0.f;
      continue;
    }
    int idx = (int)(~(unsigned int)key);
    tops[(size_t)b * TK + i] = __uint_as_float(ub);
    clsk[(size_t)b * TK + i] = cls[(size_t)b * NN + idx];
    const float* rowp = pred + ((size_t)b * NN + idx) * ROW;
    float cx = rowp[0], cy = rowp[1], w = rowp[2], h = rowp[3];
    float hw = w * 0.5f, hh = h * 0.5f;
    ob[0] = cx - hw; ob[1] = cy - hh; ob[2] = cx + hw; ob[3] = cy + hh;
  }
}

// ---------------- Stage 3: greedy NMS, one wave per (batch, class) ----------------
__global__ __launch_bounds__(64) void nms_kernel(const float* __restrict__ tops,
                                                 const float* __restrict__ boxes,
                                                 const int* __restrict__ clsk,
                                                 int* __restrict__ keep) {
  int c = blockIdx.x;
  int b = blockIdx.y;
  int lane = threadIdx.x;
  __shared__ float sx1[TK], sy1[TK], sx2[TK], sy2[TK];
  __shared__ unsigned short spos[TK];
  __shared__ unsigned char skp[TK];

  float shift = (float)c * MAXWH;
  int m = 0;
  for (int base = 0; base < TK; base += 64) {
    int j = base + lane;
    bool match = (clsk[(size_t)b * TK + j] == c);
    unsigned long long bal = __ballot(match);
    int mp = m + __popcll(bal & ((1ull << lane) - 1ull));
    if (match) {
      spos[mp] = (unsigned short)j;
      const float* bx = boxes + ((size_t)b * TK + j) * 4;
      sx1[mp] = bx[0] + shift;
      sy1[mp] = bx[1] + shift;
      sx2[mp] = bx[2] + shift;
      sy2[mp] = bx[3] + shift;
      skp[mp] = (tops[(size_t)b * TK + j] > 0.0f) ? 1 : 0;
    }
    m += (int)__popcll(bal);
  }
  __syncthreads();

  for (int i = 0; i < m; ++i) {
    __syncthreads();
    if (!skp[i]) continue;  // uniform across the wave
    float ax1 = sx1[i], ay1 = sy1[i], ax2 = sx2[i], ay2 = sy2[i];
    float aarea = (ax2 - ax1) * (ay2 - ay1);
    for (int j = i + 1 + lane; j < m; j += 64) {
      float bx1 = sx1[j], by1 = sy1[j], bx2 = sx2[j], by2 = sy2[j];
      float ltx = fmaxf(ax1, bx1), lty = fmaxf(ay1, by1);
      float rbx = fminf(ax2, bx2), rby = fminf(ay2, by2);
      float iw = fmaxf(rbx - ltx, 0.0f);
      float ih = fmaxf(rby - lty, 0.0f);
      float inter = iw * ih;
      float barea = (bx2 - bx1) * (by2 - by1);
      float iou = inter / (aarea + barea - inter + 1e-7f);
      if (iou > IOUT) skp[j] = 0;
    }
  }
  __syncthreads();

  for (int i = lane; i < m; i += 64) {
    keep[(size_t)b * TK + spos[i]] = skp[i];
  }
}

// ---------------- Stage 4: compact first 1000 kept + padding ----------------
__global__ __launch_bounds__(256) void out_kernel(const float* __restrict__ tops,
                                                  const float* __restrict__ boxes,
                                                  const int* __restrict__ clsk,
                                                  const int* __restrict__ keep,
                                                  float* __restrict__ out) {
  int b = blockIdx.x;
  int t = threadIdx.x;
  __shared__ int scnt[256];
  const int CH = TK / 256;  // 8
  int base = t * CH;
  int kp[CH];
  int cnt = 0;
  for (int k = 0; k < CH; ++k) {
    kp[k] = keep[(size_t)b * TK + base + k];
    cnt += kp[k];
  }
  scnt[t] = cnt;
  __syncthreads();
  for (int off = 1; off < 256; off <<= 1) {
    int v = (t >= off) ? scnt[t - off] : 0;
    __syncthreads();
    scnt[t] += v;
    __syncthreads();
  }
  int r = scnt[t] - cnt;
  int K = scnt[255];
  for (int k = 0; k < CH; ++k) {
    if (kp[k]) {
      if (r < MAXDET) {
        int j = base + k;
        float* o = out + ((size_t)b * MAXDET + r) * 6;
        const float* bx = boxes + ((size_t)b * TK + j) * 4;
        o[0] = bx[0]; o[1] = bx[1]; o[2] = bx[2]; o[3] = bx[3];
        o[4] = tops[(size_t)b * TK + j];
        o[5] = (float)clsk[(size_t)b * TK + j];
      }
      ++r;
    }
  }
  int Kc = K < MAXDET ? K : MAXDET;
  for (int r2 = Kc + t; r2 < MAXDET; r2 += 256) {
    float* o = out + ((size_t)b * MAXDET + r2) * 6;
    o[0] = 0.0f; o[1] = 0.0f; o[2] = 0.0f; o[3] = 0.0f; o[4] = 0.0f; o[5] = -1.0f;
  }
}

extern "C" void kernel_launch(void* const* d_in, const int* in_sizes, int n_in,
                              void* d_out, int out_size, void* d_ws, size_t ws_size,
                              hipStream_t stream) {
  const float* pred = (const float*)d_in[0];
  float* out = (float*)d_out;

  char* ws = (char*)d_ws;
  size_t off = 0;
  float* scores = (float*)(ws + off); off += (size_t)BB * NN * 4;
  int*   cls    = (int*)(ws + off);   off += (size_t)BB * NN * 4;
  float* tops   = (float*)(ws + off); off += (size_t)BB * TK * 4;
  float* boxes  = (float*)(ws + off); off += (size_t)BB * TK * 16;
  int*   clsk   = (int*)(ws + off);   off += (size_t)BB * TK * 4;
  int*   keep   = (int*)(ws + off);   off += (size_t)BB * TK * 4;
  unsigned int* hist = (unsigned int*)(ws + off); off += (size_t)BB * NBIN * 4;
  int*   pivP   = (int*)(ws + off);   off += (size_t)BB * 4;
  (void)ws_size; (void)in_sizes; (void)n_in; (void)out_size;

  hipMemsetAsync(hist, 0, (size_t)BB * NBIN * 4, stream);
  score_kernel<<<dim3((NN + 255) / 256, BB), 256, 0, stream>>>(pred, scores, cls, hist);
  pivot_kernel<<<BB, 256, 0, stream>>>(hist, pivP);
  gather_sort_kernel<<<BB, 1024, 0, stream>>>(pred, scores, cls, pivP, tops, boxes, clsk);
  nms_kernel<<<dim3(NCLS, BB), 64, 0, stream>>>(tops, boxes, clsk, keep);
  out_kernel<<<BB, 256, 0, stream>>>(tops, boxes, clsk, keep, out);
}